// Round 17
// baseline (2890.531 us; speedup 1.0000x reference)
//
#include <hip/hip_runtime.h>
#include <math.h>

// Problem constants: U=H=1024, B=32, T=256.
#define UU 1024
#define BB 32
#define TT 256
#define NCHUNK 2       // attention chunks per batch (64 dedicated att blocks)
#define GRIDN 256      // 192 GEMM + 64 attention blocks, 1 per CU
#define RING 32        // act/Pf ring depth (bounds e-lag via anti-dep wait)

// Weight pack geometry (ushort elems). Per cell: [2 planes][sections r,z,nx,nh]
#define WPS   6291456u
#define WCELL (2u * WPS)
#define SR  0u
#define SZ  2097152u
#define SNX 4194304u
#define SNH 5242880u
// Act pack: per slot [2 planes][64 ks][4 hi][32 b][8 e]; x-half [0,32768), h-half +32768
#define APS   65536u
#define ASLOT (2u * APS)
#define AEX(u, b) ((((((u) >> 5) * 4 + (((u) >> 3) & 3)) * 32 + (b)) * 8) + ((u) & 7))

// Dynamic LDS layout (bytes): [0,64K) rlo weights; [64K,112K) scratch; then red/flag.
#define SCR_OFF  65536    // 48 KB scratch (single-round combine / att ctx reduce)
#define RED_OFF  114688   // 16 f32
#define FLAG_OFF 114752
#define LDSB     114816

typedef __attribute__((ext_vector_type(8))) short bf16x8;
typedef __attribute__((ext_vector_type(4))) float f32x4;
#define MF(a, b, c) __builtin_amdgcn_mfma_f32_16x16x32_bf16((a), (b), (c), 0, 0, 0)

__device__ __forceinline__ ushort bf16rne(float v) {
    uint x = __float_as_uint(v);
    uint r = (x + 0x7fffu + ((x >> 16) & 1u)) >> 16;
    return (ushort)r;
}
__device__ __forceinline__ float ubf2f(ushort u) {
    return __uint_as_float(((uint)u) << 16);
}
__device__ __forceinline__ void split2(float v, ushort& h, ushort& l) {
    h = bf16rne(v);
    l = bf16rne(v - ubf2f(h));
}
// Agent-scope write-through stores (reach L3 directly; no wbl2 needed).
__device__ __forceinline__ void store_f32_sc(float* p, float v) {
    asm volatile("global_store_dword %0, %1, off sc1" :: "v"(p), "v"(v) : "memory");
}
__device__ __forceinline__ void store_u16_sc(ushort* p, ushort v) {
    uint vv = v;
    asm volatile("global_store_short %0, %1, off sc1" :: "v"(p), "v"(vv) : "memory");
}
__device__ __forceinline__ void vm_drain() {
    asm volatile("s_waitcnt vmcnt(0)" ::: "memory");
}
// Agent-coherent loads (read at L3 coherence point; never trust local L2).
__device__ __forceinline__ float load_f32_ag(const float* p) {
    return __hip_atomic_load(p, __ATOMIC_RELAXED, __HIP_MEMORY_SCOPE_AGENT);
}
__device__ __forceinline__ int load_i32_ag(const int* p) {
    return __hip_atomic_load(p, __ATOMIC_RELAXED, __HIP_MEMORY_SCOPE_AGENT);
}
__device__ __forceinline__ bf16x8 load_frag_ag(const ushort* p) {
    union { unsigned long long q[2]; bf16x8 v; } u;
    u.q[0] = __hip_atomic_load((const unsigned long long*)p,
                               __ATOMIC_RELAXED, __HIP_MEMORY_SCOPE_AGENT);
    u.q[1] = __hip_atomic_load((const unsigned long long*)(p + 4),
                               __ATOMIC_RELAXED, __HIP_MEMORY_SCOPE_AGENT);
    return u.v;
}

// ---------------------------------------------------------------------------
// Weight pack, all 3 cells in one launch (grid 36864; tile logic proven).
// ---------------------------------------------------------------------------
__global__ void packw_kernel(const float* __restrict__ gWih, const float* __restrict__ gWhh,
                             const float* __restrict__ pWih, const float* __restrict__ pWhh,
                             const float* __restrict__ eWih, const float* __restrict__ eWhh,
                             ushort* __restrict__ wpack) {
    int cellb = blockIdx.x / 12288;
    int tile = blockIdx.x - cellb * 12288;
    const float* Wih = (cellb == 0) ? gWih : (cellb == 1) ? pWih : eWih;
    const float* Whh = (cellb == 0) ? gWhh : (cellb == 1) ? pWhh : eWhh;
    ushort* wp = wpack + (size_t)cellb * WCELL;
    int sec, jt, ks, nks;
    size_t soff;
    if (tile < 8192) {
        sec = tile >> 12; int l = tile & 4095; jt = l >> 6; ks = l & 63; nks = 64;
        soff = sec ? SZ : SR;
    } else {
        int l2 = tile - 8192; sec = 2 + (l2 >> 11); int l = l2 & 2047; jt = l >> 5; ks = l & 31; nks = 32;
        soff = (sec == 2) ? SNX : SNH;
    }
    int p = threadIdx.x;
    int e0 = (p & 3) * 2, ul = (p >> 2) & 15, hi = p >> 6;
    int u = jt * 16 + ul;
    int kk = ks * 32 + hi * 8 + e0;
    float2 w;
    if (sec < 2) {
        int row = (sec ? 1024 : 0) + u;
        if (kk < 1024) w = *(const float2*)&Wih[(size_t)row * UU + kk];
        else           w = *(const float2*)&Whh[(size_t)row * UU + kk - 1024];
    } else if (sec == 2) {
        w = *(const float2*)&Wih[(size_t)(2048 + u) * UU + kk];
    } else {
        w = *(const float2*)&Whh[(size_t)(2048 + u) * UU + kk];
    }
    ushort h0, l0, h1, l1;
    split2(w.x, h0, l0); split2(w.y, h1, l1);
    size_t ob = soff + ((((size_t)jt * nks + ks) * 4 + hi) * 16 + ul) * 8 + e0;
    *(uint*)(wp + ob)       = (uint)h0 | ((uint)h1 << 16);
    *(uint*)(wp + WPS + ob) = (uint)l0 | ((uint)l1 << 16);
}

// ---------------------------------------------------------------------------
// q_all[t][b][u] = sum_k inputs[b][t][k] * global_W[k][u]  (fp32)
// Register-blocked 256x128 tile GEMM; k-order ascending (bitwise-stable).
// ---------------------------------------------------------------------------
__global__ __launch_bounds__(256)
void qall_kernel(const float* __restrict__ x,
                 const float* __restrict__ gW,
                 float* __restrict__ q) {
    __shared__ float xs[16][257];   // [k][r]
    __shared__ float gws[16][128];  // [k][n]
    const int r0 = blockIdx.x * 256, n0 = blockIdx.y * 128;
    const int tid = threadIdx.x;
    const int tr = tid & 31, tn = tid >> 5;
    float acc[8][16];
    #pragma unroll
    for (int i = 0; i < 8; ++i)
        #pragma unroll
        for (int j = 0; j < 16; ++j) acc[i][j] = 0.f;
    for (int k0 = 0; k0 < UU; k0 += 16) {
        {   // stage x: 256 rows x 16 k
            int rr = tid >> 2;
            const int f4 = (tid & 3) * 4;
            #pragma unroll
            for (int it = 0; it < 4; ++it, rr += 64) {
                const int r = r0 + rr;
                const int tt = r >> 5, bb = r & 31;
                float4 v = *(const float4*)&x[((size_t)bb * TT + tt) * UU + k0 + f4];
                xs[f4][rr] = v.x; xs[f4 + 1][rr] = v.y;
                xs[f4 + 2][rr] = v.z; xs[f4 + 3][rr] = v.w;
            }
        }
        {   // stage gW: 16 k x 128 n
            int kr = tid >> 5;
            const int nn = (tid & 31) * 4;
            #pragma unroll
            for (int it = 0; it < 2; ++it, kr += 8) {
                float4 v = *(const float4*)&gW[(size_t)(k0 + kr) * UU + n0 + nn];
                *(float4*)&gws[kr][nn] = v;
            }
        }
        __syncthreads();
        #pragma unroll
        for (int kk = 0; kk < 16; ++kk) {
            float xv[8];
            #pragma unroll
            for (int i = 0; i < 8; ++i) xv[i] = xs[kk][tr + 32 * i];
            float gv[16];
            #pragma unroll
            for (int j4 = 0; j4 < 4; ++j4) {
                float4 g = *(const float4*)&gws[kk][tn * 16 + j4 * 4];
                gv[j4 * 4] = g.x; gv[j4 * 4 + 1] = g.y;
                gv[j4 * 4 + 2] = g.z; gv[j4 * 4 + 3] = g.w;
            }
            #pragma unroll
            for (int i = 0; i < 8; ++i)
                #pragma unroll
                for (int j = 0; j < 16; ++j)
                    acc[i][j] += xv[i] * gv[j];
        }
        __syncthreads();
    }
    #pragma unroll
    for (int i = 0; i < 8; ++i) {
        const int r = r0 + tr + 32 * i;
        #pragma unroll
        for (int j4 = 0; j4 < 4; ++j4) {
            float4 v = {acc[i][j4 * 4], acc[i][j4 * 4 + 1],
                        acc[i][j4 * 4 + 2], acc[i][j4 * 4 + 3]};
            *(float4*)&q[(size_t)r * UU + n0 + tn * 16 + j4 * 4] = v;
        }
    }
}

// ---------------------------------------------------------------------------
// Init. bar layout (ints):
//   [0]=g_rel  [32]=p_rel  [64]=e_rel
//   [128 + cell*128 + slot*32] = class arrival ring counters (slot<4, monotone)
//   [512 + ab*16] = per-ab finisher-done counter
// cnt[ab] = att pair-arrival counter.
// ---------------------------------------------------------------------------
__global__ void init_kernel(const float* __restrict__ inputs,
                            const float* __restrict__ gbih, const float* __restrict__ gbhh,
                            const float* __restrict__ pbih, const float* __restrict__ pbhh,
                            const float* __restrict__ ebih, const float* __restrict__ ebhh,
                            float* __restrict__ hist, float* __restrict__ Pf,
                            ushort* __restrict__ gpack, ushort* __restrict__ ppack,
                            ushort* __restrict__ epack, float* __restrict__ biasp,
                            int* __restrict__ cnt, int* __restrict__ bar) {
    if (blockIdx.x == 0) {
        if (threadIdx.x < 32) cnt[threadIdx.x] = 0;
        for (int i = threadIdx.x; i < 1024; i += 256) bar[i] = 0;
    }
    if (blockIdx.x < 128) {
        int i = blockIdx.x * 256 + threadIdx.x;
        int b = i >> 10, u = i & 1023;
        hist[i] = 0.f;
        Pf[i] = 0.f; Pf[32768 + i] = 0.f;   // Pf slots 0 (t=0) and 1 (t=1)
        int ex = AEX(u, b);
        int eh = ex + 32768;
        gpack[eh] = 0; gpack[APS + eh] = 0;
        ppack[eh] = 0; ppack[APS + eh] = 0;
        ppack[ASLOT + eh] = 0; ppack[ASLOT + APS + eh] = 0;
        epack[eh] = 0; epack[APS + eh] = 0;
        float x0 = inputs[((size_t)b * TT + 0) * UU + u];
        float x1 = inputs[((size_t)b * TT + 1) * UU + u];
        ushort h, l;
        split2(x0, h, l); gpack[ex] = h; gpack[APS + ex] = l;
        split2(x1, h, l); gpack[ASLOT + ex] = h; gpack[ASLOT + APS + ex] = l;
    } else {
        int idx = (blockIdx.x - 128) * 256 + threadIdx.x;
        int cell = idx >> 12, g4 = (idx >> 10) & 3, u = idx & 1023;
        const float* bih = (cell == 0) ? gbih : (cell == 1) ? pbih : ebih;
        const float* bhh = (cell == 0) ? gbhh : (cell == 1) ? pbhh : ebhh;
        float v;
        if (g4 == 0) v = bih[u] + bhh[u];
        else if (g4 == 1) v = bih[1024 + u] + bhh[1024 + u];
        else if (g4 == 2) v = bih[2048 + u];
        else v = bhh[2048 + u];
        biasp[idx] = v;
    }
}

// ---------------------------------------------------------------------------
// Persistent kernel v3.3: round-15/16 dataflow (passing), with
//  (a) zlo weights moved LDS->VGPR; only rlo in LDS (64 KB)
//  (b) single-round gate combine in 48 KB scratch (2 syncs/step, not 6);
//      per-gate FP summation order unchanged -> bitwise-identical output
//  (c) poll sleep 8->2.
// Waits / rings / cache policy identical to round 16 (see its comments).
// ---------------------------------------------------------------------------
__global__ __launch_bounds__(512)
__attribute__((amdgpu_waves_per_eu(2)))
void persist_kernel(const float* __restrict__ inputs,
                    const ushort* __restrict__ wpack,
                    const float* __restrict__ biasp,
                    ushort* __restrict__ gpack, ushort* __restrict__ ppack,
                    ushort* __restrict__ epack,
                    float* __restrict__ hist, float* __restrict__ Pf,
                    const float* __restrict__ qall,
                    float* __restrict__ out,
                    float* __restrict__ attC, float* __restrict__ attML,
                    int* __restrict__ cnt, int* __restrict__ bar) {
    extern __shared__ char smraw[];
    float* lds_scr  = (float*)(smraw + SCR_OFF);
    float* lds_red  = (float*)(smraw + RED_OFF);
    int*   lds_flag = (int*)(smraw + FLAG_OFF);

    const int blk = blockIdx.x, tid = threadIdx.x;
    const int cell = blk >> 6, jt = blk & 63;       // cell 3 => attention block
    const int w = tid >> 6, lane = tid & 63;
    const int l15 = lane & 15, hi4 = lane >> 4;
    const int ab = blk & 31, ac = (blk >> 5) & 1;   // attention task
    const ushort* wp = wpack + (size_t)cell * WCELL;

    if (cell < 3) {
        // ================= GEMM class (g / p / e) =================
        bf16x8 whiR[8], whiZ[8], wloZ[8], whiN[8], wloN[8];
        const int ebt = tid >> 8, eli = (tid >> 2) & 63, ei = tid & 3;
        const int eb = ebt * 16 + (eli & 15);
        const int eu = jt * 16 + (eli >> 4) * 4 + ei;
        const int eex = AEX(eu, eb);
        #pragma unroll
        for (int i = 0; i < 8; ++i) {
            const int ks = w * 8 + i;
            const size_t aoff = ((size_t)(jt * 256 + ks * 4 + hi4)) * 128 + (size_t)l15 * 8;
            whiR[i] = *(const bf16x8*)(wp + SR + aoff);
            whiZ[i] = *(const bf16x8*)(wp + SZ + aoff);
            bf16x8 rlo = *(const bf16x8*)(wp + SR + WPS + aoff);
            wloZ[i] = *(const bf16x8*)(wp + SZ + WPS + aoff);
            *(bf16x8*)(smraw + (((w * 8 + i) * 64 + lane) << 4)) = rlo;
            const int ksn = (w & 3) * 8 + i;
            const size_t noff = ((size_t)(jt * 128 + ksn * 4 + hi4)) * 128 + (size_t)l15 * 8;
            const size_t sN = (w < 4) ? SNX : SNH;
            whiN[i] = *(const bf16x8*)(wp + sN + noff);
            wloN[i] = *(const bf16x8*)(wp + sN + WPS + noff);
        }
        const float* bc = biasp + cell * 4096;
        const float bR = bc[eu], bZ = bc[1024 + eu];
        const float bNI = bc[2048 + eu], bNH = bc[3072 + eu];
        ushort* apk = (cell == 0) ? gpack : (cell == 1) ? ppack : epack;
        __syncthreads();

        for (int tc = 0; tc < TT; ++tc) {
            // ---- lane-parallel min-progress waits (wave 0) ----
            if (w == 0) {
                const int* wptr; int wneed;
                if (cell == 0) {
                    if (lane == 0)      { wptr = bar;       wneed = tc; }      // g_rel
                    else if (lane == 1) { wptr = bar + 32;  wneed = tc - 1; }  // p_rel
                    else                { wptr = bar;       wneed = -2147483647; }
                } else if (cell == 1) {
                    if (lane < 32)       { wptr = bar + 512 + lane * 16; wneed = tc + 1; } // fin[all]
                    else if (lane == 32) { wptr = bar + 32; wneed = tc - 1; }  // p_rel
                    else if (lane == 33) { wptr = bar + 64; wneed = tc - 31; } // e_rel
                    else                 { wptr = bar;      wneed = -2147483647; }
                } else {
                    if (lane == 0)      { wptr = bar + 32;  wneed = tc + 1; }  // p_rel
                    else if (lane == 1) { wptr = bar + 64;  wneed = tc; }      // e_rel
                    else                { wptr = bar;       wneed = -2147483647; }
                }
                while (!__all(load_i32_ag(wptr) >= wneed))
                    __builtin_amdgcn_s_sleep(2);
            }
            __syncthreads();
            f32x4 aR0 = {0,0,0,0}, aR1 = {0,0,0,0};
            f32x4 aZ0 = {0,0,0,0}, aZ1 = {0,0,0,0};
            f32x4 aN0 = {0,0,0,0}, aN1 = {0,0,0,0};
            const ushort* ap = apk + (size_t)(tc & (RING - 1)) * ASLOT;
            const ushort* bbp = ap + ((size_t)hi4 * 32 + l15) * 8;
            #pragma unroll
            for (int i = 0; i < 8; ++i) {
                const int ks = w * 8 + i;
                const ushort* bp = bbp + (size_t)ks * 1024;
                bf16x8 bh0 = load_frag_ag(bp);
                bf16x8 bh1 = load_frag_ag(bp + 128);
                bf16x8 bl0 = load_frag_ag(bp + APS);
                bf16x8 bl1 = load_frag_ag(bp + APS + 128);
                bf16x8 rlo = *(const bf16x8*)(smraw + (((w * 8 + i) * 64 + lane) << 4));
                aR0 = MF(whiR[i], bh0, aR0); aR0 = MF(whiR[i], bl0, aR0); aR0 = MF(rlo, bh0, aR0);
                aR1 = MF(whiR[i], bh1, aR1); aR1 = MF(whiR[i], bl1, aR1); aR1 = MF(rlo, bh1, aR1);
                aZ0 = MF(whiZ[i], bh0, aZ0); aZ0 = MF(whiZ[i], bl0, aZ0); aZ0 = MF(wloZ[i], bh0, aZ0);
                aZ1 = MF(whiZ[i], bh1, aZ1); aZ1 = MF(whiZ[i], bl1, aZ1); aZ1 = MF(wloZ[i], bh1, aZ1);
                aN0 = MF(whiN[i], bh0, aN0); aN0 = MF(whiN[i], bl0, aN0); aN0 = MF(wloN[i], bh0, aN0);
                aN1 = MF(whiN[i], bh1, aN1); aN1 = MF(whiN[i], bl1, aN1); aN1 = MF(wloN[i], bh1, aN1);
            }
            // ---- single-round combine into registers (48 KB scratch) ----
            // scratch index: (((gate*2 + part)*8 + w)*64 + lane)*4 ; gate 0=R,1=Z,2=N
            *(f32x4*)&lds_scr[(((0 * 2 + 0) * 8 + w) * 64 + lane) * 4] = aR0;
            *(f32x4*)&lds_scr[(((0 * 2 + 1) * 8 + w) * 64 + lane) * 4] = aR1;
            *(f32x4*)&lds_scr[(((1 * 2 + 0) * 8 + w) * 64 + lane) * 4] = aZ0;
            *(f32x4*)&lds_scr[(((1 * 2 + 1) * 8 + w) * 64 + lane) * 4] = aZ1;
            *(f32x4*)&lds_scr[(((2 * 2 + 0) * 8 + w) * 64 + lane) * 4] = aN0;
            *(f32x4*)&lds_scr[(((2 * 2 + 1) * 8 + w) * 64 + lane) * 4] = aN1;
            __syncthreads();
            float R = 0.f, Z = 0.f, iN = 0.f, hN = 0.f;
            #pragma unroll
            for (int w2 = 0; w2 < 8; ++w2)
                R += lds_scr[(((0 * 2 + ebt) * 8 + w2) * 64 + eli) * 4 + ei];
            #pragma unroll
            for (int w2 = 0; w2 < 8; ++w2)
                Z += lds_scr[(((1 * 2 + ebt) * 8 + w2) * 64 + eli) * 4 + ei];
            #pragma unroll
            for (int w2 = 0; w2 < 4; ++w2)
                iN += lds_scr[(((2 * 2 + ebt) * 8 + w2) * 64 + eli) * 4 + ei];
            #pragma unroll
            for (int w2 = 4; w2 < 8; ++w2)
                hN += lds_scr[(((2 * 2 + ebt) * 8 + w2) * 64 + eli) * 4 + ei];
            // ---- epilogue (1 output/thread), cross-block stores sc1 ----
            {
                float hprev;
                if (cell == 0)      hprev = hist[((size_t)tc * BB + eb) * UU + eu];
                else if (cell == 1) hprev = load_f32_ag(&Pf[(size_t)(tc & (RING - 1)) * BB * UU + (size_t)eb * UU + eu]);
                else                hprev = (tc > 0) ? out[((size_t)eb * TT + tc - 1) * UU + eu] : 0.f;
                const float r = 1.f / (1.f + expf(-(R + bR)));
                const float z = 1.f / (1.f + expf(-(Z + bZ)));
                const float n2 = tanhf(iN + bNI + r * (hN + bNH));
                const float val = (1.f - z) * n2 + z * hprev;
                ushort vh, vl; split2(val, vh, vl);
                if (cell == 0) {
                    store_f32_sc(&hist[((size_t)(tc + 1) * BB + eb) * UU + eu], val);
                    ushort* d = gpack + (size_t)((tc + 1) & (RING - 1)) * ASLOT;
                    store_u16_sc(d + eex + 32768, vh);
                    store_u16_sc(d + APS + eex + 32768, vl);
                } else if (cell == 1) {
                    ushort* d = epack + (size_t)(tc & (RING - 1)) * ASLOT;
                    store_u16_sc(d + eex, vh);
                    store_u16_sc(d + APS + eex, vl);
                    if (tc + 2 < TT) {
                        store_f32_sc(&Pf[(size_t)((tc + 2) & (RING - 1)) * BB * UU + (size_t)eb * UU + eu], val);
                        ushort* d2 = ppack + (size_t)((tc + 2) & (RING - 1)) * ASLOT;
                        store_u16_sc(d2 + eex + 32768, vh);
                        store_u16_sc(d2 + APS + eex + 32768, vl);
                        const float gx = val + inputs[((size_t)eb * TT + tc + 2) * UU + eu];
                        ushort gh, gl; split2(gx, gh, gl);
                        ushort* d3 = gpack + (size_t)((tc + 2) & (RING - 1)) * ASLOT;
                        store_u16_sc(d3 + eex, gh);
                        store_u16_sc(d3 + APS + eex, gl);
                    }
                } else {
                    store_f32_sc(&out[((size_t)eb * TT + tc) * UU + eu], val);
                    if (tc + 1 < TT) {
                        ushort* d = epack + (size_t)((tc + 1) & (RING - 1)) * ASLOT;
                        store_u16_sc(d + eex + 32768, vh);
                        store_u16_sc(d + APS + eex + 32768, vl);
                    }
                }
            }
            vm_drain();
            __syncthreads();
            if (tid == 0) {
                int* ring = bar + 128 + cell * 128 + (tc & 3) * 32;
                int old = __hip_atomic_fetch_add(ring, 1, __ATOMIC_RELAXED,
                                                 __HIP_MEMORY_SCOPE_AGENT);
                if ((old & 63) == 63) {
                    (void)__hip_atomic_fetch_max(bar + cell * 32, tc + 1,
                                                 __ATOMIC_RELAXED, __HIP_MEMORY_SCOPE_AGENT);
                }
            }
        }
    } else {
        // ================= attention class (ac, ab) =================
        int* fin = bar + 512 + ab * 16;
        for (int t = 0; t < TT; ++t) {
            if (w == 0) {
                const int* wptr; int wneed;
                if (lane == 0)      { wptr = bar; wneed = t; }   // g_rel >= t
                else if (lane == 1) { wptr = fin; wneed = t; }   // finisher of t-1 done
                else                { wptr = bar; wneed = -2147483647; }
                while (!__all(load_i32_ag(wptr) >= wneed))
                    __builtin_amdgcn_s_sleep(2);
            }
            __syncthreads();
            const int slot = t & 3;
            float* aC = attC + (((size_t)slot * NCHUNK + ac) * BB + ab) * UU;
            float* aML = attML + (((size_t)slot * NCHUNK + ac) * BB + ab) * 2;
            const int nt2 = t + 1;
            const int cstr = (nt2 + NCHUNK - 1) / NCHUNK;
            const int r0 = ac * cstr;
            const int r1x = r0 + cstr;
            const int r1 = (r1x < nt2) ? r1x : nt2;
            const int n = r1 - r0;
            if (n <= 0) {
                #pragma unroll
                for (int rep = 0; rep < 2; ++rep)
                    store_f32_sc(aC + tid + rep * 512, 0.f);
                if (tid == 0) {
                    store_f32_sc(aML, -INFINITY);
                    store_f32_sc(aML + 1, 0.f);
                }
            } else {
                const float* qb = qall + ((size_t)t * BB + ab) * UU;
                float4 q0 = *(const float4*)&qb[lane * 4];
                float4 q1 = *(const float4*)&qb[256 + lane * 4];
                float4 q2 = *(const float4*)&qb[512 + lane * 4];
                float4 q3 = *(const float4*)&qb[768 + lane * 4];
                float m_run = -INFINITY, l_run = 0.f;
                float4 c0 = {0,0,0,0}, c1 = {0,0,0,0}, c2 = {0,0,0,0}, c3 = {0,0,0,0};
                for (int tp = r0 + w; tp < r1; tp += 8) {
                    const float* hr = hist + ((size_t)tp * BB + ab) * UU;
                    float4 h0 = *(const float4*)&hr[lane * 4];
                    float4 h1 = *(const float4*)&hr[256 + lane * 4];
                    float4 h2 = *(const float4*)&hr[512 + lane * 4];
                    float4 h3 = *(const float4*)&hr[768 + lane * 4];
                    float s = h0.x*q0.x + h0.y*q0.y + h0.z*q0.z + h0.w*q0.w
                            + h1.x*q1.x + h1.y*q1.y + h1.z*q1.z + h1.w*q1.w
                            + h2.x*q2.x + h2.y*q2.y + h2.z*q2.z + h2.w*q2.w
                            + h3.x*q3.x + h3.y*q3.y + h3.z*q3.z + h3.w*q3.w;
                    #pragma unroll
                    for (int off = 32; off; off >>= 1) s += __shfl_xor(s, off);
                    const float mn = fmaxf(m_run, s);
                    const float sc = expf(m_run - mn);
                    const float e2 = expf(s - mn);
                    c0.x = c0.x*sc + e2*h0.x; c0.y = c0.y*sc + e2*h0.y; c0.z = c0.z*sc + e2*h0.z; c0.w = c0.w*sc + e2*h0.w;
                    c1.x = c1.x*sc + e2*h1.x; c1.y = c1.y*sc + e2*h1.y; c1.z = c1.z*sc + e2*h1.z; c1.w = c1.w*sc + e2*h1.w;
                    c2.x = c2.x*sc + e2*h2.x; c2.y = c2.y*sc + e2*h2.y; c2.z = c2.z*sc + e2*h2.z; c2.w = c2.w*sc + e2*h2.w;
                    c3.x = c3.x*sc + e2*h3.x; c3.y = c3.y*sc + e2*h3.y; c3.z = c3.z*sc + e2*h3.z; c3.w = c3.w*sc + e2*h3.w;
                    l_run = l_run * sc + e2;
                    m_run = mn;
                }
                *(float4*)&lds_scr[w * 512 + lane * 4] = c0;
                *(float4*)&lds_scr[w * 512 + 256 + lane * 4] = c1;
                if (lane == 0) { lds_red[w] = m_run; lds_red[8 + w] = l_run; }
                __syncthreads();
                float M = lds_red[0];
                #pragma unroll
                for (int k = 1; k < 8; ++k) M = fmaxf(M, lds_red[k]);
                float ww[8], L = 0.f;
                #pragma unroll
                for (int k = 0; k < 8; ++k) { ww[k] = expf(lds_red[k] - M); L += ww[k] * lds_red[8 + k]; }
                if (tid == 0) {
                    store_f32_sc(aML, M);
                    store_f32_sc(aML + 1, L);
                }
                {
                    float s = 0.f;
                    #pragma unroll
                    for (int w2 = 0; w2 < 8; ++w2) s += ww[w2] * lds_scr[w2 * 512 + tid];
                    store_f32_sc(aC + tid, s);
                }
                __syncthreads();
                *(float4*)&lds_scr[w * 512 + lane * 4] = c2;
                *(float4*)&lds_scr[w * 512 + 256 + lane * 4] = c3;
                __syncthreads();
                {
                    float s = 0.f;
                    #pragma unroll
                    for (int w2 = 0; w2 < 8; ++w2) s += ww[w2] * lds_scr[w2 * 512 + tid];
                    store_f32_sc(aC + 512 + tid, s);
                }
            }
            // publish chunk, pair handshake (arrivals for step t are {2t, 2t+1})
            vm_drain();
            __syncthreads();
            if (tid == 0) {
                int old = __hip_atomic_fetch_add(cnt + ab, 1, __ATOMIC_RELAXED,
                                                 __HIP_MEMORY_SCOPE_AGENT);
                lds_flag[0] = (old & 1);
            }
            __syncthreads();
            if (lds_flag[0]) {
                // Finisher (2nd arriver of this step): merge 2 partials (agent loads).
                float mm[NCHUNK], ll[NCHUNK];
                #pragma unroll
                for (int c = 0; c < NCHUNK; ++c) {
                    const float* ml = attML + (((size_t)slot * NCHUNK + c) * BB + ab) * 2;
                    mm[c] = load_f32_ag(ml);
                    ll[c] = load_f32_ag(ml + 1);
                }
                float M2 = mm[0];
                #pragma unroll
                for (int c = 1; c < NCHUNK; ++c) M2 = fmaxf(M2, mm[c]);
                float den = 0.f, wc[NCHUNK];
                #pragma unroll
                for (int c = 0; c < NCHUNK; ++c) { wc[c] = expf(mm[c] - M2); den += wc[c] * ll[c]; }
                const float inv = 1.f / den;
                ushort* d = ppack + (size_t)(t & (RING - 1)) * ASLOT;
                #pragma unroll
                for (int rep = 0; rep < 2; ++rep) {
                    const int e = tid + rep * 512;
                    float s3 = 0.f;
                    #pragma unroll
                    for (int c = 0; c < NCHUNK; ++c)
                        s3 += wc[c] * load_f32_ag(&attC[(((size_t)slot * NCHUNK + c) * BB + ab) * UU + e]);
                    const float xv = s3 * inv + inputs[((size_t)ab * TT + t) * UU + e];
                    ushort vh2, vl2; split2(xv, vh2, vl2);
                    const int ex2 = AEX(e, ab);
                    store_u16_sc(d + ex2, vh2);
                    store_u16_sc(d + APS + ex2, vl2);
                }
                vm_drain();
            }
            __syncthreads();
            if (tid == 0 && lds_flag[0])
                __hip_atomic_fetch_add(fin, 1, __ATOMIC_RELAXED, __HIP_MEMORY_SCOPE_AGENT);
        }
    }
}

extern "C" void kernel_launch(void* const* d_in, const int* in_sizes, int n_in,
                              void* d_out, int out_size, void* d_ws, size_t ws_size,
                              hipStream_t stream) {
    (void)in_sizes; (void)n_in; (void)out_size; (void)ws_size;
    const float* inputs = (const float*)d_in[0];
    const float* gW   = (const float*)d_in[1];
    const float* gWih = (const float*)d_in[2];
    const float* gWhh = (const float*)d_in[3];
    const float* gbih = (const float*)d_in[4];
    const float* gbhh = (const float*)d_in[5];
    const float* pWih = (const float*)d_in[6];
    const float* pWhh = (const float*)d_in[7];
    const float* pbih = (const float*)d_in[8];
    const float* pbhh = (const float*)d_in[9];
    const float* eWih = (const float*)d_in[10];
    const float* eWhh = (const float*)d_in[11];
    const float* ebih = (const float*)d_in[12];
    const float* ebhh = (const float*)d_in[13];
    float* out = (float*)d_out;

    char* ws = (char*)d_ws;
    size_t off = 0;
    auto alloc = [&](size_t bytes) {
        void* p = ws + off;
        off += (bytes + 255) & ~(size_t)255;
        return p;
    };
    ushort* wpack = (ushort*)alloc((size_t)3 * WCELL * 2);
    ushort* gpack = (ushort*)alloc((size_t)RING * ASLOT * 2);
    ushort* ppack = (ushort*)alloc((size_t)RING * ASLOT * 2);
    ushort* epack = (ushort*)alloc((size_t)RING * ASLOT * 2);
    float* hist  = (float*)alloc((size_t)(TT + 1) * BB * UU * 4);
    float* qall  = (float*)alloc((size_t)TT * BB * UU * 4);
    float* Pf    = (float*)alloc((size_t)RING * BB * UU * 4);
    float* biasp = (float*)alloc((size_t)3 * 4096 * 4);
    float* attC  = (float*)alloc((size_t)4 * NCHUNK * BB * UU * 4);   // 4-slot parity
    float* attML = (float*)alloc((size_t)4 * NCHUNK * BB * 2 * 4);
    int*   cnt   = (int*)alloc(32 * 4);
    int*   bar   = (int*)alloc(1024 * 4);

    packw_kernel<<<36864, 256, 0, stream>>>(gWih, gWhh, pWih, pWhh, eWih, eWhh, wpack);
    qall_kernel<<<dim3(32, 8), 256, 0, stream>>>(inputs, gW, qall);
    init_kernel<<<176, 256, 0, stream>>>(inputs, gbih, gbhh, pbih, pbhh, ebih, ebhh,
                                         hist, Pf, gpack, ppack, epack, biasp, cnt, bar);

    hipFuncSetAttribute((const void*)persist_kernel,
                        hipFuncAttributeMaxDynamicSharedMemorySize, LDSB);
    void* args[] = {(void*)&inputs, (void*)&wpack, (void*)&biasp,
                    (void*)&gpack, (void*)&ppack, (void*)&epack,
                    (void*)&hist, (void*)&Pf, (void*)&qall, (void*)&out,
                    (void*)&attC, (void*)&attML, (void*)&cnt, (void*)&bar};
    hipError_t ce = hipLaunchCooperativeKernel((const void*)persist_kernel,
                                               dim3(GRIDN), dim3(512), args,
                                               (unsigned)LDSB, stream);
    if (ce != hipSuccess) {
        (void)hipGetLastError();
        // 256 blocks at 1 block/CU on a 256-CU part are co-resident; the
        // monotone-counter dataflow is safe under a plain launch too.
        persist_kernel<<<GRIDN, 512, LDSB, stream>>>(inputs, wpack, biasp,
                                                     gpack, ppack, epack,
                                                     hist, Pf, qall, out,
                                                     attC, attML, cnt, bar);
    }
}

// Round 18
// 2832.855 us; speedup vs baseline: 1.0204x; 1.0204x over previous
//
#include <hip/hip_runtime.h>
#include <math.h>

// Problem constants: U=H=1024, B=32, T=256.
#define UU 1024
#define BB 32
#define TT 256
#define NCHUNK 2       // attention chunks per batch (64 dedicated att blocks)
#define GRIDN 256      // 192 GEMM + 64 attention blocks, 1 per CU
#define RING 32        // act/Pf ring depth (bounds e-lag via anti-dep wait)

// Weight pack geometry (ushort elems). Per cell: [2 planes][sections r,z,nx,nh]
#define WPS   6291456u
#define WCELL (2u * WPS)
#define SR  0u
#define SZ  2097152u
#define SNX 4194304u
#define SNH 5242880u
// Act pack: per slot [2 planes][64 ks][4 hi][32 b][8 e]; x-half [0,32768), h-half +32768
#define APS   65536u
#define ASLOT (2u * APS)
#define AEX(u, b) ((((((u) >> 5) * 4 + (((u) >> 3) & 3)) * 32 + (b)) * 8) + ((u) & 7))

// Dynamic LDS layout (bytes): [0,128K) r/z lo-plane weights; then scratch.
#define SCR_OFF  131072   // 16 KB scratch (combine dumps / att ctx reduce)
#define RED_OFF  147456   // 16 f32
#define FLAG_OFF 147520
#define LDSB     147584

typedef __attribute__((ext_vector_type(8))) short bf16x8;
typedef __attribute__((ext_vector_type(4))) float f32x4;
#define MF(a, b, c) __builtin_amdgcn_mfma_f32_16x16x32_bf16((a), (b), (c), 0, 0, 0)

__device__ __forceinline__ ushort bf16rne(float v) {
    uint x = __float_as_uint(v);
    uint r = (x + 0x7fffu + ((x >> 16) & 1u)) >> 16;
    return (ushort)r;
}
__device__ __forceinline__ float ubf2f(ushort u) {
    return __uint_as_float(((uint)u) << 16);
}
__device__ __forceinline__ void split2(float v, ushort& h, ushort& l) {
    h = bf16rne(v);
    l = bf16rne(v - ubf2f(h));
}
// Agent-scope write-through stores (reach L3 directly; no wbl2 needed).
__device__ __forceinline__ void store_f32_sc(float* p, float v) {
    asm volatile("global_store_dword %0, %1, off sc1" :: "v"(p), "v"(v) : "memory");
}
__device__ __forceinline__ void store_u16_sc(ushort* p, ushort v) {
    uint vv = v;
    asm volatile("global_store_short %0, %1, off sc1" :: "v"(p), "v"(vv) : "memory");
}
__device__ __forceinline__ void vm_drain() {
    asm volatile("s_waitcnt vmcnt(0)" ::: "memory");
}
// Agent-coherent loads (read at L3 coherence point; never trust local L2).
__device__ __forceinline__ float load_f32_ag(const float* p) {
    return __hip_atomic_load(p, __ATOMIC_RELAXED, __HIP_MEMORY_SCOPE_AGENT);
}
__device__ __forceinline__ int load_i32_ag(const int* p) {
    return __hip_atomic_load(p, __ATOMIC_RELAXED, __HIP_MEMORY_SCOPE_AGENT);
}
__device__ __forceinline__ bf16x8 load_frag_ag(const ushort* p) {
    union { unsigned long long q[2]; bf16x8 v; } u;
    u.q[0] = __hip_atomic_load((const unsigned long long*)p,
                               __ATOMIC_RELAXED, __HIP_MEMORY_SCOPE_AGENT);
    u.q[1] = __hip_atomic_load((const unsigned long long*)(p + 4),
                               __ATOMIC_RELAXED, __HIP_MEMORY_SCOPE_AGENT);
    return u.v;
}

// ---------------------------------------------------------------------------
// Weight pack, all 3 cells in one launch (grid 36864; tile logic proven).
// ---------------------------------------------------------------------------
__global__ void packw_kernel(const float* __restrict__ gWih, const float* __restrict__ gWhh,
                             const float* __restrict__ pWih, const float* __restrict__ pWhh,
                             const float* __restrict__ eWih, const float* __restrict__ eWhh,
                             ushort* __restrict__ wpack) {
    int cellb = blockIdx.x / 12288;
    int tile = blockIdx.x - cellb * 12288;
    const float* Wih = (cellb == 0) ? gWih : (cellb == 1) ? pWih : eWih;
    const float* Whh = (cellb == 0) ? gWhh : (cellb == 1) ? pWhh : eWhh;
    ushort* wp = wpack + (size_t)cellb * WCELL;
    int sec, jt, ks, nks;
    size_t soff;
    if (tile < 8192) {
        sec = tile >> 12; int l = tile & 4095; jt = l >> 6; ks = l & 63; nks = 64;
        soff = sec ? SZ : SR;
    } else {
        int l2 = tile - 8192; sec = 2 + (l2 >> 11); int l = l2 & 2047; jt = l >> 5; ks = l & 31; nks = 32;
        soff = (sec == 2) ? SNX : SNH;
    }
    int p = threadIdx.x;
    int e0 = (p & 3) * 2, ul = (p >> 2) & 15, hi = p >> 6;
    int u = jt * 16 + ul;
    int kk = ks * 32 + hi * 8 + e0;
    float2 w;
    if (sec < 2) {
        int row = (sec ? 1024 : 0) + u;
        if (kk < 1024) w = *(const float2*)&Wih[(size_t)row * UU + kk];
        else           w = *(const float2*)&Whh[(size_t)row * UU + kk - 1024];
    } else if (sec == 2) {
        w = *(const float2*)&Wih[(size_t)(2048 + u) * UU + kk];
    } else {
        w = *(const float2*)&Whh[(size_t)(2048 + u) * UU + kk];
    }
    ushort h0, l0, h1, l1;
    split2(w.x, h0, l0); split2(w.y, h1, l1);
    size_t ob = soff + ((((size_t)jt * nks + ks) * 4 + hi) * 16 + ul) * 8 + e0;
    *(uint*)(wp + ob)       = (uint)h0 | ((uint)h1 << 16);
    *(uint*)(wp + WPS + ob) = (uint)l0 | ((uint)l1 << 16);
}

// ---------------------------------------------------------------------------
// q_all[t][b][u] = sum_k inputs[b][t][k] * global_W[k][u]  (fp32)
// Register-blocked 256x128 tile GEMM; k-order ascending (bitwise-stable).
// ---------------------------------------------------------------------------
__global__ __launch_bounds__(256)
void qall_kernel(const float* __restrict__ x,
                 const float* __restrict__ gW,
                 float* __restrict__ q) {
    __shared__ float xs[16][257];   // [k][r]
    __shared__ float gws[16][128];  // [k][n]
    const int r0 = blockIdx.x * 256, n0 = blockIdx.y * 128;
    const int tid = threadIdx.x;
    const int tr = tid & 31, tn = tid >> 5;
    float acc[8][16];
    #pragma unroll
    for (int i = 0; i < 8; ++i)
        #pragma unroll
        for (int j = 0; j < 16; ++j) acc[i][j] = 0.f;
    for (int k0 = 0; k0 < UU; k0 += 16) {
        {   // stage x: 256 rows x 16 k
            int rr = tid >> 2;
            const int f4 = (tid & 3) * 4;
            #pragma unroll
            for (int it = 0; it < 4; ++it, rr += 64) {
                const int r = r0 + rr;
                const int tt = r >> 5, bb = r & 31;
                float4 v = *(const float4*)&x[((size_t)bb * TT + tt) * UU + k0 + f4];
                xs[f4][rr] = v.x; xs[f4 + 1][rr] = v.y;
                xs[f4 + 2][rr] = v.z; xs[f4 + 3][rr] = v.w;
            }
        }
        {   // stage gW: 16 k x 128 n
            int kr = tid >> 5;
            const int nn = (tid & 31) * 4;
            #pragma unroll
            for (int it = 0; it < 2; ++it, kr += 8) {
                float4 v = *(const float4*)&gW[(size_t)(k0 + kr) * UU + n0 + nn];
                *(float4*)&gws[kr][nn] = v;
            }
        }
        __syncthreads();
        #pragma unroll
        for (int kk = 0; kk < 16; ++kk) {
            float xv[8];
            #pragma unroll
            for (int i = 0; i < 8; ++i) xv[i] = xs[kk][tr + 32 * i];
            float gv[16];
            #pragma unroll
            for (int j4 = 0; j4 < 4; ++j4) {
                float4 g = *(const float4*)&gws[kk][tn * 16 + j4 * 4];
                gv[j4 * 4] = g.x; gv[j4 * 4 + 1] = g.y;
                gv[j4 * 4 + 2] = g.z; gv[j4 * 4 + 3] = g.w;
            }
            #pragma unroll
            for (int i = 0; i < 8; ++i)
                #pragma unroll
                for (int j = 0; j < 16; ++j)
                    acc[i][j] += xv[i] * gv[j];
        }
        __syncthreads();
    }
    #pragma unroll
    for (int i = 0; i < 8; ++i) {
        const int r = r0 + tr + 32 * i;
        #pragma unroll
        for (int j4 = 0; j4 < 4; ++j4) {
            float4 v = {acc[i][j4 * 4], acc[i][j4 * 4 + 1],
                        acc[i][j4 * 4 + 2], acc[i][j4 * 4 + 3]};
            *(float4*)&q[(size_t)r * UU + n0 + tn * 16 + j4 * 4] = v;
        }
    }
}

// ---------------------------------------------------------------------------
// Init. bar layout (ints):
//   [0]=g_rel  [32]=p_rel  [64]=e_rel
//   [128 + cell*128 + slot*32] = class ROOT arrival counters (slot<4)
//   [512 + ab*16] = per-ab finisher-done counter
//   [1024 + ((cell*4+slot)*8+leaf)*32] = class LEAF arrival counters (leaf<8)
// cnt[ab] = att pair-arrival counter.
// ---------------------------------------------------------------------------
__global__ void init_kernel(const float* __restrict__ inputs,
                            const float* __restrict__ gbih, const float* __restrict__ gbhh,
                            const float* __restrict__ pbih, const float* __restrict__ pbhh,
                            const float* __restrict__ ebih, const float* __restrict__ ebhh,
                            float* __restrict__ hist, float* __restrict__ Pf,
                            ushort* __restrict__ gpack, ushort* __restrict__ ppack,
                            ushort* __restrict__ epack, float* __restrict__ biasp,
                            int* __restrict__ cnt, int* __restrict__ bar) {
    if (blockIdx.x == 0) {
        if (threadIdx.x < 32) cnt[threadIdx.x] = 0;
        for (int i = threadIdx.x; i < 4096; i += 256) bar[i] = 0;
    }
    if (blockIdx.x < 128) {
        int i = blockIdx.x * 256 + threadIdx.x;
        int b = i >> 10, u = i & 1023;
        hist[i] = 0.f;
        Pf[i] = 0.f; Pf[32768 + i] = 0.f;   // Pf slots 0 (t=0) and 1 (t=1)
        int ex = AEX(u, b);
        int eh = ex + 32768;
        gpack[eh] = 0; gpack[APS + eh] = 0;
        ppack[eh] = 0; ppack[APS + eh] = 0;
        ppack[ASLOT + eh] = 0; ppack[ASLOT + APS + eh] = 0;
        epack[eh] = 0; epack[APS + eh] = 0;
        float x0 = inputs[((size_t)b * TT + 0) * UU + u];
        float x1 = inputs[((size_t)b * TT + 1) * UU + u];
        ushort h, l;
        split2(x0, h, l); gpack[ex] = h; gpack[APS + ex] = l;
        split2(x1, h, l); gpack[ASLOT + ex] = h; gpack[ASLOT + APS + ex] = l;
    } else {
        int idx = (blockIdx.x - 128) * 256 + threadIdx.x;
        int cell = idx >> 12, g4 = (idx >> 10) & 3, u = idx & 1023;
        const float* bih = (cell == 0) ? gbih : (cell == 1) ? pbih : ebih;
        const float* bhh = (cell == 0) ? gbhh : (cell == 1) ? pbhh : ebhh;
        float v;
        if (g4 == 0) v = bih[u] + bhh[u];
        else if (g4 == 1) v = bih[1024 + u] + bhh[1024 + u];
        else if (g4 == 2) v = bih[2048 + u];
        else v = bhh[2048 + u];
        biasp[idx] = v;
    }
}

// ---------------------------------------------------------------------------
// Persistent kernel v3.4: round-16 dataflow (passing, 2828 us) with ONE change:
// class arrivals are TWO-LEVEL (8 leaf counters x 8 blocks -> root -> release)
// to cut same-cacheline RMW serialization 64 -> 8+8.
// Epoch soundness: class self-wait serializes epochs per slot; releases
// serialize root epochs; so (old mod groupsize)==groupsize-1 uniquely marks
// epoch completion at each level (same induction as the flat version).
// Everything else identical to round 16 (waits/rings/cache policy/combine).
// ---------------------------------------------------------------------------
__global__ __launch_bounds__(512)
__attribute__((amdgpu_waves_per_eu(2)))
void persist_kernel(const float* __restrict__ inputs,
                    const ushort* __restrict__ wpack,
                    const float* __restrict__ biasp,
                    ushort* __restrict__ gpack, ushort* __restrict__ ppack,
                    ushort* __restrict__ epack,
                    float* __restrict__ hist, float* __restrict__ Pf,
                    const float* __restrict__ qall,
                    float* __restrict__ out,
                    float* __restrict__ attC, float* __restrict__ attML,
                    int* __restrict__ cnt, int* __restrict__ bar) {
    extern __shared__ char smraw[];
    float* lds_scr  = (float*)(smraw + SCR_OFF);
    float* lds_red  = (float*)(smraw + RED_OFF);
    int*   lds_flag = (int*)(smraw + FLAG_OFF);

    const int blk = blockIdx.x, tid = threadIdx.x;
    const int cell = blk >> 6, jt = blk & 63;       // cell 3 => attention block
    const int w = tid >> 6, lane = tid & 63;
    const int l15 = lane & 15, hi4 = lane >> 4;
    const int ab = blk & 31, ac = (blk >> 5) & 1;   // attention task
    const ushort* wp = wpack + (size_t)cell * WCELL;

    if (cell < 3) {
        // ================= GEMM class (g / p / e) =================
        bf16x8 whiR[8], whiZ[8], whiN[8], wloN[8];
        const int ebt = tid >> 8, eli = (tid >> 2) & 63, ei = tid & 3;
        const int eb = ebt * 16 + (eli & 15);
        const int eu = jt * 16 + (eli >> 4) * 4 + ei;
        const int eex = AEX(eu, eb);
        #pragma unroll
        for (int i = 0; i < 8; ++i) {
            const int ks = w * 8 + i;
            const size_t aoff = ((size_t)(jt * 256 + ks * 4 + hi4)) * 128 + (size_t)l15 * 8;
            whiR[i] = *(const bf16x8*)(wp + SR + aoff);
            whiZ[i] = *(const bf16x8*)(wp + SZ + aoff);
            bf16x8 rlo = *(const bf16x8*)(wp + SR + WPS + aoff);
            bf16x8 zlo = *(const bf16x8*)(wp + SZ + WPS + aoff);
            *(bf16x8*)(smraw + (((w * 16 + i) * 64 + lane) << 4)) = rlo;
            *(bf16x8*)(smraw + (((w * 16 + 8 + i) * 64 + lane) << 4)) = zlo;
            const int ksn = (w & 3) * 8 + i;
            const size_t noff = ((size_t)(jt * 128 + ksn * 4 + hi4)) * 128 + (size_t)l15 * 8;
            const size_t sN = (w < 4) ? SNX : SNH;
            whiN[i] = *(const bf16x8*)(wp + sN + noff);
            wloN[i] = *(const bf16x8*)(wp + sN + WPS + noff);
        }
        const float* bc = biasp + cell * 4096;
        const float bR = bc[eu], bZ = bc[1024 + eu];
        const float bNI = bc[2048 + eu], bNH = bc[3072 + eu];
        ushort* apk = (cell == 0) ? gpack : (cell == 1) ? ppack : epack;
        __syncthreads();

        for (int tc = 0; tc < TT; ++tc) {
            // ---- lane-parallel min-progress waits (wave 0) ----
            if (w == 0) {
                const int* wptr; int wneed;
                if (cell == 0) {
                    if (lane == 0)      { wptr = bar;       wneed = tc; }      // g_rel
                    else if (lane == 1) { wptr = bar + 32;  wneed = tc - 1; }  // p_rel
                    else                { wptr = bar;       wneed = -2147483647; }
                } else if (cell == 1) {
                    if (lane < 32)       { wptr = bar + 512 + lane * 16; wneed = tc + 1; } // fin[all]
                    else if (lane == 32) { wptr = bar + 32; wneed = tc - 1; }  // p_rel
                    else if (lane == 33) { wptr = bar + 64; wneed = tc - 31; } // e_rel
                    else                 { wptr = bar;      wneed = -2147483647; }
                } else {
                    if (lane == 0)      { wptr = bar + 32;  wneed = tc + 1; }  // p_rel
                    else if (lane == 1) { wptr = bar + 64;  wneed = tc; }      // e_rel
                    else                { wptr = bar;       wneed = -2147483647; }
                }
                while (!__all(load_i32_ag(wptr) >= wneed))
                    __builtin_amdgcn_s_sleep(8);
            }
            __syncthreads();
            f32x4 aR0 = {0,0,0,0}, aR1 = {0,0,0,0};
            f32x4 aZ0 = {0,0,0,0}, aZ1 = {0,0,0,0};
            f32x4 aN0 = {0,0,0,0}, aN1 = {0,0,0,0};
            const ushort* ap = apk + (size_t)(tc & (RING - 1)) * ASLOT;
            const ushort* bbp = ap + ((size_t)hi4 * 32 + l15) * 8;
            #pragma unroll
            for (int i = 0; i < 8; ++i) {
                const int ks = w * 8 + i;
                const ushort* bp = bbp + (size_t)ks * 1024;
                bf16x8 bh0 = load_frag_ag(bp);
                bf16x8 bh1 = load_frag_ag(bp + 128);
                bf16x8 bl0 = load_frag_ag(bp + APS);
                bf16x8 bl1 = load_frag_ag(bp + APS + 128);
                bf16x8 rlo = *(const bf16x8*)(smraw + (((w * 16 + i) * 64 + lane) << 4));
                bf16x8 zlo = *(const bf16x8*)(smraw + (((w * 16 + 8 + i) * 64 + lane) << 4));
                aR0 = MF(whiR[i], bh0, aR0); aR0 = MF(whiR[i], bl0, aR0); aR0 = MF(rlo, bh0, aR0);
                aR1 = MF(whiR[i], bh1, aR1); aR1 = MF(whiR[i], bl1, aR1); aR1 = MF(rlo, bh1, aR1);
                aZ0 = MF(whiZ[i], bh0, aZ0); aZ0 = MF(whiZ[i], bl0, aZ0); aZ0 = MF(zlo, bh0, aZ0);
                aZ1 = MF(whiZ[i], bh1, aZ1); aZ1 = MF(whiZ[i], bl1, aZ1); aZ1 = MF(zlo, bh1, aZ1);
                aN0 = MF(whiN[i], bh0, aN0); aN0 = MF(whiN[i], bl0, aN0); aN0 = MF(wloN[i], bh0, aN0);
                aN1 = MF(whiN[i], bh1, aN1); aN1 = MF(whiN[i], bl1, aN1); aN1 = MF(wloN[i], bh1, aN1);
            }
            // ---- combine into registers (combiner thread == epilogue thread) ----
            float R, Z, iN, hN;
            *(f32x4*)&lds_scr[((0 * 8 + w) * 64 + lane) * 4] = aR0;
            *(f32x4*)&lds_scr[((1 * 8 + w) * 64 + lane) * 4] = aR1;
            __syncthreads();
            {
                float s = 0.f;
                #pragma unroll
                for (int w2 = 0; w2 < 8; ++w2) s += lds_scr[((ebt * 8 + w2) * 64 + eli) * 4 + ei];
                R = s;
            }
            __syncthreads();
            *(f32x4*)&lds_scr[((0 * 8 + w) * 64 + lane) * 4] = aZ0;
            *(f32x4*)&lds_scr[((1 * 8 + w) * 64 + lane) * 4] = aZ1;
            __syncthreads();
            {
                float s = 0.f;
                #pragma unroll
                for (int w2 = 0; w2 < 8; ++w2) s += lds_scr[((ebt * 8 + w2) * 64 + eli) * 4 + ei];
                Z = s;
            }
            __syncthreads();
            *(f32x4*)&lds_scr[((0 * 8 + w) * 64 + lane) * 4] = aN0;
            *(f32x4*)&lds_scr[((1 * 8 + w) * 64 + lane) * 4] = aN1;
            __syncthreads();
            {
                float si = 0.f, sh = 0.f;
                #pragma unroll
                for (int w2 = 0; w2 < 4; ++w2) si += lds_scr[((ebt * 8 + w2) * 64 + eli) * 4 + ei];
                #pragma unroll
                for (int w2 = 4; w2 < 8; ++w2) sh += lds_scr[((ebt * 8 + w2) * 64 + eli) * 4 + ei];
                iN = si; hN = sh;
            }
            // ---- epilogue (1 output/thread), cross-block stores sc1 ----
            {
                float hprev;
                if (cell == 0)      hprev = hist[((size_t)tc * BB + eb) * UU + eu];
                else if (cell == 1) hprev = load_f32_ag(&Pf[(size_t)(tc & (RING - 1)) * BB * UU + (size_t)eb * UU + eu]);
                else                hprev = (tc > 0) ? out[((size_t)eb * TT + tc - 1) * UU + eu] : 0.f;
                const float r = 1.f / (1.f + expf(-(R + bR)));
                const float z = 1.f / (1.f + expf(-(Z + bZ)));
                const float n2 = tanhf(iN + bNI + r * (hN + bNH));
                const float val = (1.f - z) * n2 + z * hprev;
                ushort vh, vl; split2(val, vh, vl);
                if (cell == 0) {
                    store_f32_sc(&hist[((size_t)(tc + 1) * BB + eb) * UU + eu], val);
                    ushort* d = gpack + (size_t)((tc + 1) & (RING - 1)) * ASLOT;
                    store_u16_sc(d + eex + 32768, vh);
                    store_u16_sc(d + APS + eex + 32768, vl);
                } else if (cell == 1) {
                    ushort* d = epack + (size_t)(tc & (RING - 1)) * ASLOT;
                    store_u16_sc(d + eex, vh);
                    store_u16_sc(d + APS + eex, vl);
                    if (tc + 2 < TT) {
                        store_f32_sc(&Pf[(size_t)((tc + 2) & (RING - 1)) * BB * UU + (size_t)eb * UU + eu], val);
                        ushort* d2 = ppack + (size_t)((tc + 2) & (RING - 1)) * ASLOT;
                        store_u16_sc(d2 + eex + 32768, vh);
                        store_u16_sc(d2 + APS + eex + 32768, vl);
                        const float gx = val + inputs[((size_t)eb * TT + tc + 2) * UU + eu];
                        ushort gh, gl; split2(gx, gh, gl);
                        ushort* d3 = gpack + (size_t)((tc + 2) & (RING - 1)) * ASLOT;
                        store_u16_sc(d3 + eex, gh);
                        store_u16_sc(d3 + APS + eex, gl);
                    }
                } else {
                    store_f32_sc(&out[((size_t)eb * TT + tc) * UU + eu], val);
                    if (tc + 1 < TT) {
                        ushort* d = epack + (size_t)((tc + 1) & (RING - 1)) * ASLOT;
                        store_u16_sc(d + eex + 32768, vh);
                        store_u16_sc(d + APS + eex + 32768, vl);
                    }
                }
            }
            vm_drain();
            __syncthreads();
            if (tid == 0) {
                // two-level arrival: leaf (8 blocks) -> root (8 leaves) -> release
                int* leaf = bar + 1024 + (((cell * 4 + (tc & 3)) * 8 + (jt >> 3)) << 5);
                int old = __hip_atomic_fetch_add(leaf, 1, __ATOMIC_RELAXED,
                                                 __HIP_MEMORY_SCOPE_AGENT);
                if ((old & 7) == 7) {
                    int* root = bar + 128 + cell * 128 + (tc & 3) * 32;
                    int ro = __hip_atomic_fetch_add(root, 1, __ATOMIC_RELAXED,
                                                    __HIP_MEMORY_SCOPE_AGENT);
                    if ((ro & 7) == 7) {
                        (void)__hip_atomic_fetch_max(bar + cell * 32, tc + 1,
                                                     __ATOMIC_RELAXED, __HIP_MEMORY_SCOPE_AGENT);
                    }
                }
            }
        }
    } else {
        // ================= attention class (ac, ab) =================
        int* fin = bar + 512 + ab * 16;
        for (int t = 0; t < TT; ++t) {
            if (w == 0) {
                const int* wptr; int wneed;
                if (lane == 0)      { wptr = bar; wneed = t; }   // g_rel >= t
                else if (lane == 1) { wptr = fin; wneed = t; }   // finisher of t-1 done
                else                { wptr = bar; wneed = -2147483647; }
                while (!__all(load_i32_ag(wptr) >= wneed))
                    __builtin_amdgcn_s_sleep(8);
            }
            __syncthreads();
            const int slot = t & 3;
            float* aC = attC + (((size_t)slot * NCHUNK + ac) * BB + ab) * UU;
            float* aML = attML + (((size_t)slot * NCHUNK + ac) * BB + ab) * 2;
            const int nt2 = t + 1;
            const int cstr = (nt2 + NCHUNK - 1) / NCHUNK;
            const int r0 = ac * cstr;
            const int r1x = r0 + cstr;
            const int r1 = (r1x < nt2) ? r1x : nt2;
            const int n = r1 - r0;
            if (n <= 0) {
                #pragma unroll
                for (int rep = 0; rep < 2; ++rep)
                    store_f32_sc(aC + tid + rep * 512, 0.f);
                if (tid == 0) {
                    store_f32_sc(aML, -INFINITY);
                    store_f32_sc(aML + 1, 0.f);
                }
            } else {
                const float* qb = qall + ((size_t)t * BB + ab) * UU;
                float4 q0 = *(const float4*)&qb[lane * 4];
                float4 q1 = *(const float4*)&qb[256 + lane * 4];
                float4 q2 = *(const float4*)&qb[512 + lane * 4];
                float4 q3 = *(const float4*)&qb[768 + lane * 4];
                float m_run = -INFINITY, l_run = 0.f;
                float4 c0 = {0,0,0,0}, c1 = {0,0,0,0}, c2 = {0,0,0,0}, c3 = {0,0,0,0};
                for (int tp = r0 + w; tp < r1; tp += 8) {
                    const float* hr = hist + ((size_t)tp * BB + ab) * UU;
                    float4 h0 = *(const float4*)&hr[lane * 4];
                    float4 h1 = *(const float4*)&hr[256 + lane * 4];
                    float4 h2 = *(const float4*)&hr[512 + lane * 4];
                    float4 h3 = *(const float4*)&hr[768 + lane * 4];
                    float s = h0.x*q0.x + h0.y*q0.y + h0.z*q0.z + h0.w*q0.w
                            + h1.x*q1.x + h1.y*q1.y + h1.z*q1.z + h1.w*q1.w
                            + h2.x*q2.x + h2.y*q2.y + h2.z*q2.z + h2.w*q2.w
                            + h3.x*q3.x + h3.y*q3.y + h3.z*q3.z + h3.w*q3.w;
                    #pragma unroll
                    for (int off = 32; off; off >>= 1) s += __shfl_xor(s, off);
                    const float mn = fmaxf(m_run, s);
                    const float sc = expf(m_run - mn);
                    const float e2 = expf(s - mn);
                    c0.x = c0.x*sc + e2*h0.x; c0.y = c0.y*sc + e2*h0.y; c0.z = c0.z*sc + e2*h0.z; c0.w = c0.w*sc + e2*h0.w;
                    c1.x = c1.x*sc + e2*h1.x; c1.y = c1.y*sc + e2*h1.y; c1.z = c1.z*sc + e2*h1.z; c1.w = c1.w*sc + e2*h1.w;
                    c2.x = c2.x*sc + e2*h2.x; c2.y = c2.y*sc + e2*h2.y; c2.z = c2.z*sc + e2*h2.z; c2.w = c2.w*sc + e2*h2.w;
                    c3.x = c3.x*sc + e2*h3.x; c3.y = c3.y*sc + e2*h3.y; c3.z = c3.z*sc + e2*h3.z; c3.w = c3.w*sc + e2*h3.w;
                    l_run = l_run * sc + e2;
                    m_run = mn;
                }
                *(float4*)&lds_scr[w * 512 + lane * 4] = c0;
                *(float4*)&lds_scr[w * 512 + 256 + lane * 4] = c1;
                if (lane == 0) { lds_red[w] = m_run; lds_red[8 + w] = l_run; }
                __syncthreads();
                float M = lds_red[0];
                #pragma unroll
                for (int k = 1; k < 8; ++k) M = fmaxf(M, lds_red[k]);
                float ww[8], L = 0.f;
                #pragma unroll
                for (int k = 0; k < 8; ++k) { ww[k] = expf(lds_red[k] - M); L += ww[k] * lds_red[8 + k]; }
                if (tid == 0) {
                    store_f32_sc(aML, M);
                    store_f32_sc(aML + 1, L);
                }
                {
                    float s = 0.f;
                    #pragma unroll
                    for (int w2 = 0; w2 < 8; ++w2) s += ww[w2] * lds_scr[w2 * 512 + tid];
                    store_f32_sc(aC + tid, s);
                }
                __syncthreads();
                *(float4*)&lds_scr[w * 512 + lane * 4] = c2;
                *(float4*)&lds_scr[w * 512 + 256 + lane * 4] = c3;
                __syncthreads();
                {
                    float s = 0.f;
                    #pragma unroll
                    for (int w2 = 0; w2 < 8; ++w2) s += ww[w2] * lds_scr[w2 * 512 + tid];
                    store_f32_sc(aC + 512 + tid, s);
                }
            }
            // publish chunk, pair handshake (arrivals for step t are {2t, 2t+1})
            vm_drain();
            __syncthreads();
            if (tid == 0) {
                int old = __hip_atomic_fetch_add(cnt + ab, 1, __ATOMIC_RELAXED,
                                                 __HIP_MEMORY_SCOPE_AGENT);
                lds_flag[0] = (old & 1);
            }
            __syncthreads();
            if (lds_flag[0]) {
                // Finisher (2nd arriver of this step): merge 2 partials (agent loads).
                float mm[NCHUNK], ll[NCHUNK];
                #pragma unroll
                for (int c = 0; c < NCHUNK; ++c) {
                    const float* ml = attML + (((size_t)slot * NCHUNK + c) * BB + ab) * 2;
                    mm[c] = load_f32_ag(ml);
                    ll[c] = load_f32_ag(ml + 1);
                }
                float M2 = mm[0];
                #pragma unroll
                for (int c = 1; c < NCHUNK; ++c) M2 = fmaxf(M2, mm[c]);
                float den = 0.f, wc[NCHUNK];
                #pragma unroll
                for (int c = 0; c < NCHUNK; ++c) { wc[c] = expf(mm[c] - M2); den += wc[c] * ll[c]; }
                const float inv = 1.f / den;
                ushort* d = ppack + (size_t)(t & (RING - 1)) * ASLOT;
                #pragma unroll
                for (int rep = 0; rep < 2; ++rep) {
                    const int e = tid + rep * 512;
                    float s3 = 0.f;
                    #pragma unroll
                    for (int c = 0; c < NCHUNK; ++c)
                        s3 += wc[c] * load_f32_ag(&attC[(((size_t)slot * NCHUNK + c) * BB + ab) * UU + e]);
                    const float xv = s3 * inv + inputs[((size_t)ab * TT + t) * UU + e];
                    ushort vh2, vl2; split2(xv, vh2, vl2);
                    const int ex2 = AEX(e, ab);
                    store_u16_sc(d + ex2, vh2);
                    store_u16_sc(d + APS + ex2, vl2);
                }
                vm_drain();
            }
            __syncthreads();
            if (tid == 0 && lds_flag[0])
                __hip_atomic_fetch_add(fin, 1, __ATOMIC_RELAXED, __HIP_MEMORY_SCOPE_AGENT);
        }
    }
}

extern "C" void kernel_launch(void* const* d_in, const int* in_sizes, int n_in,
                              void* d_out, int out_size, void* d_ws, size_t ws_size,
                              hipStream_t stream) {
    (void)in_sizes; (void)n_in; (void)out_size; (void)ws_size;
    const float* inputs = (const float*)d_in[0];
    const float* gW   = (const float*)d_in[1];
    const float* gWih = (const float*)d_in[2];
    const float* gWhh = (const float*)d_in[3];
    const float* gbih = (const float*)d_in[4];
    const float* gbhh = (const float*)d_in[5];
    const float* pWih = (const float*)d_in[6];
    const float* pWhh = (const float*)d_in[7];
    const float* pbih = (const float*)d_in[8];
    const float* pbhh = (const float*)d_in[9];
    const float* eWih = (const float*)d_in[10];
    const float* eWhh = (const float*)d_in[11];
    const float* ebih = (const float*)d_in[12];
    const float* ebhh = (const float*)d_in[13];
    float* out = (float*)d_out;

    char* ws = (char*)d_ws;
    size_t off = 0;
    auto alloc = [&](size_t bytes) {
        void* p = ws + off;
        off += (bytes + 255) & ~(size_t)255;
        return p;
    };
    ushort* wpack = (ushort*)alloc((size_t)3 * WCELL * 2);
    ushort* gpack = (ushort*)alloc((size_t)RING * ASLOT * 2);
    ushort* ppack = (ushort*)alloc((size_t)RING * ASLOT * 2);
    ushort* epack = (ushort*)alloc((size_t)RING * ASLOT * 2);
    float* hist  = (float*)alloc((size_t)(TT + 1) * BB * UU * 4);
    float* qall  = (float*)alloc((size_t)TT * BB * UU * 4);
    float* Pf    = (float*)alloc((size_t)RING * BB * UU * 4);
    float* biasp = (float*)alloc((size_t)3 * 4096 * 4);
    float* attC  = (float*)alloc((size_t)4 * NCHUNK * BB * UU * 4);   // 4-slot parity
    float* attML = (float*)alloc((size_t)4 * NCHUNK * BB * 2 * 4);
    int*   cnt   = (int*)alloc(32 * 4);
    int*   bar   = (int*)alloc(4096 * 4);

    packw_kernel<<<36864, 256, 0, stream>>>(gWih, gWhh, pWih, pWhh, eWih, eWhh, wpack);
    qall_kernel<<<dim3(32, 8), 256, 0, stream>>>(inputs, gW, qall);
    init_kernel<<<176, 256, 0, stream>>>(inputs, gbih, gbhh, pbih, pbhh, ebih, ebhh,
                                         hist, Pf, gpack, ppack, epack, biasp, cnt, bar);

    hipFuncSetAttribute((const void*)persist_kernel,
                        hipFuncAttributeMaxDynamicSharedMemorySize, LDSB);
    void* args[] = {(void*)&inputs, (void*)&wpack, (void*)&biasp,
                    (void*)&gpack, (void*)&ppack, (void*)&epack,
                    (void*)&hist, (void*)&Pf, (void*)&qall, (void*)&out,
                    (void*)&attC, (void*)&attML, (void*)&cnt, (void*)&bar};
    hipError_t ce = hipLaunchCooperativeKernel((const void*)persist_kernel,
                                               dim3(GRIDN), dim3(512), args,
                                               (unsigned)LDSB, stream);
    if (ce != hipSuccess) {
        (void)hipGetLastError();
        // 256 blocks at 1 block/CU on a 256-CU part are co-resident; the
        // monotone-counter dataflow is safe under a plain launch too.
        persist_kernel<<<GRIDN, 512, LDSB, stream>>>(inputs, wpack, biasp,
                                                     gpack, ppack, epack,
                                                     hist, Pf, qall, out,
                                                     attC, attML, cnt, bar);
    }
}